// Round 9
// baseline (287.660 us; speedup 1.0000x reference)
//
#include <hip/hip_runtime.h>
#include <hip/hip_cooperative_groups.h>
#include <math.h>

namespace cg = cooperative_groups;

// ---------------- problem constants ----------------
#define NIMG   8
#define NA     15
#define GH     100
#define GW     100
#define HW     10000
#define HWA    150000      // NA*HW
#define NSLICE 12
#define F4S    3125        // float4s per slice (NSLICE*F4S*4 == HWA)
#define SLEN   12500       // elements per slice
#define PRE    2000
#define POST   1000
#define CAP    4096        // sort buffer capacity
#define RCAP   512         // per-slice candidate region (mean ~285, 13.7 sigma)
#define NBINS  2048
#define MROWS  2048        // mask rows per image (padded past PRE)
#define B0     1365        // fixed conservative bin cutoff = logit_bin(2.0)
#define NBLK   128
#define BBOX_CLIP_F 4.135166556742356f
#define IMGSZ  1600.0f
#define BINSCALE 170.6666667f   // NBINS / 12 over logit range [-6,6]

// ---------------- workspace layout (bytes) ----------------
// No init needed: every byte consumed is written by an earlier phase this call.
#define WS_PCNT   0u            // u32 [96]             384
#define WS_CAND   384u          // u64 [96][512]        393216 -> 393600
#define WS_PHIST  393600u       // u32 [96][2048]       786432 -> 1180032
#define WS_TOPB   1180032u      // f32 [8][2000][4]     256000 -> 1436032
#define WS_TOPS   1436032u      // f32 [8][2000]        64000  -> 1500032 (+256 pad)
#define WS_MASK   1500288u      // u64 [8][2048][32]    4194304 -> 5694592

// s_waitcnt imm: vmcnt[3:0]+[15:14], expcnt[6:4]=7 (ignore), lgkmcnt[11:8]=15 (ignore)
#define WAIT_VM(n) __builtin_amdgcn_s_waitcnt(((n)&15)|(((n)>>4)<<14)|0xF70)
#define WAIT_LGKM0 __builtin_amdgcn_s_waitcnt(0xC07F)   // lgkmcnt(0), vmcnt=63

// async global->LDS DMA, 16 B/lane, zero VGPR results
__device__ __forceinline__ void gl_lds16(const void* g, void* l) {
    __builtin_amdgcn_global_load_lds(
        (const __attribute__((address_space(1))) unsigned int*)g,
        (__attribute__((address_space(3))) unsigned int*)l, 16, 0, 0);
}

// Correctly-rounded f32 exp via double, feeding an IEEE f32 add/div chain.
// Models CPU-reference sigmoid. VERIFIED bit-exact R1-R8.
__device__ __forceinline__ float ref_exp_f32(float x) {
    return (float)exp((double)x);
}
__device__ __forceinline__ float ref_sigmoid(float x) {
    float t = ref_exp_f32(-x);
    return __fdiv_rn(1.0f, __fadd_rn(1.0f, t));
}

// monotone logit->bin map
__device__ __forceinline__ int logit_bin(float x) {
    int b = (int)floorf(__fmul_rn(__fadd_rn(x, 6.0f), BINSCALE));
    return max(0, min(NBINS - 1, b));
}

// 64-bit wave-uniform broadcast via scalar readlane
__device__ __forceinline__ unsigned long long rl64(unsigned long long v, int l) {
    unsigned lo = (unsigned)__builtin_amdgcn_readlane((int)(unsigned)v, l);
    unsigned hi = (unsigned)__builtin_amdgcn_readlane((int)(unsigned)(v >> 32), l);
    return ((unsigned long long)hi << 32) | (unsigned long long)lo;
}

__device__ __forceinline__ unsigned long long mk_key(float x, int e) {
    unsigned sb = __float_as_uint(ref_sigmoid(x));
    unsigned j = (unsigned)((e % HW) * NA + e / HW);   // flat anchor index
    return ((unsigned long long)sb << 32) | (unsigned long long)(0xFFFFFFFFu - j);
}

union SharedU {
    struct {                                   // phase 1: hist + compact staging
        unsigned hist[NBINS];                  // 8 KB
        unsigned long long lbuf[RCAP];         // 4 KB
        unsigned lcnt;
    } p1;
    struct {                                   // phase 2: b* + gather + sort
        unsigned hist[NBINS];                  // 8 KB
        unsigned long long sk[CAP];            // 32 KB
        unsigned lcnt;
        int bs, fb, off[NSLICE + 1];
    } p2;
    struct {                                   // phase 3: iou boxes SoA
        float X1[PRE], Y1[PRE], X2[PRE], Y2[PRE];   // 32 KB
    } p3;
    struct {                                   // phase 4: nms
        unsigned long long sbuf[2][2048];      // 32 KB staging
        float sval[2048];                      // 8 KB
        unsigned short kept[POST];
        int cnt;
    } p4;
};

__global__ void __launch_bounds__(1024) mega(
        const float* __restrict__ obj,
        const float* __restrict__ deltas,
        unsigned* __restrict__ pcnt,
        unsigned long long* __restrict__ cand,
        unsigned* __restrict__ phist,
        float* __restrict__ topb,
        float* __restrict__ tops,
        unsigned long long* __restrict__ mask,
        float* __restrict__ out) {
    __shared__ SharedU su;
    cg::grid_group grid = cg::this_grid();
    const int tid = threadIdx.x;

    // ================= PHASE 1: hist + B0-compact (single obj scan) ==========
    if (blockIdx.x < NIMG * NSLICE) {
        const int n = blockIdx.x & 7, slice = blockIdx.x >> 3;
        for (int t = tid; t < NBINS; t += 1024) su.p1.hist[t] = 0u;
        if (tid == 0) su.p1.lcnt = 0u;
        __syncthreads();
        const float4* op4 = (const float4*)(obj + (size_t)n * HWA) + (size_t)slice * F4S;
        const int ebase = slice * SLEN;
        for (int t = tid; t < F4S; t += 1024) {
            float4 v = op4[t];
            float xs[4] = {v.x, v.y, v.z, v.w};
            #pragma unroll
            for (int k = 0; k < 4; ++k) {
                int b = logit_bin(xs[k]);
                atomicAdd(&su.p1.hist[b], 1u);
                if (b >= B0) {
                    unsigned p = atomicAdd(&su.p1.lcnt, 1u);
                    if (p < RCAP) su.p1.lbuf[p] = mk_key(xs[k], ebase + t * 4 + k);
                }
            }
        }
        __syncthreads();
        const int r = n * NSLICE + slice;
        unsigned* ph = phist + (size_t)r * NBINS;
        for (int t = tid; t < NBINS; t += 1024) ph[t] = su.p1.hist[t];
        const unsigned L = su.p1.lcnt;
        if (tid == 0) pcnt[r] = L;                 // raw (may exceed RCAP -> fallback)
        const unsigned Lc = (L < RCAP) ? L : RCAP;
        unsigned long long* cp = cand + (size_t)r * RCAP;
        for (unsigned t = tid; t < Lc; t += 1024) cp[t] = su.p1.lbuf[t];
    }
    grid.sync();

    // ================= PHASE 2: exact b* + gather + sort + decode ============
    if (blockIdx.x < NIMG) {
        const int n = blockIdx.x;
        // sum the 12 partial hists
        const unsigned* ph = phist + (size_t)n * NSLICE * NBINS;
        for (int b = tid; b < NBINS; b += 1024) {
            unsigned s = 0;
            #pragma unroll
            for (int k = 0; k < NSLICE; ++k) s += ph[k * NBINS + b];
            su.p2.hist[b] = s;
        }
        __syncthreads();
        // wave 0: b* = max{b : sum_{x>=b} hist[x] >= PRE} (0 if total < PRE)
        if (tid < 64) {
            const int lane = tid;
            unsigned v[32]; unsigned S = 0;
            #pragma unroll
            for (int t = 0; t < 32; ++t) { v[t] = su.p2.hist[lane * 32 + t]; S += v[t]; }
            unsigned T = S;
            #pragma unroll
            for (int d = 1; d < 64; d <<= 1) {
                unsigned u = __shfl_down(T, d);
                if (lane + d < 64) T += u;
            }
            unsigned Tn = T - S;
            int bestt = -1; unsigned W = 0;
            #pragma unroll
            for (int t = 31; t >= 0; --t) {
                W += v[t];
                if (bestt < 0 && W + Tn >= PRE) bestt = t;
            }
            unsigned long long hm = __ballot(bestt >= 0);
            int bs = 0;
            if (hm != 0ull) {
                int hl = 63 - __builtin_clzll(hm);
                int bt = __builtin_amdgcn_readlane(bestt, hl);
                bs = hl * 32 + bt;
            }
            if (lane == 0) su.p2.bs = bs;
        }
        // slice counts -> offsets, fallback detection
        if (tid < NSLICE) su.p2.off[tid + 1] = (int)pcnt[n * NSLICE + tid];
        __syncthreads();
        if (tid == 0) {
            int fb = (su.p2.bs < B0) ? 1 : 0;
            int acc = 0;
            su.p2.off[0] = 0;
            for (int s = 0; s < NSLICE; ++s) {
                int c = su.p2.off[s + 1];
                if (c > RCAP) { fb = 1; c = RCAP; }
                acc += c;
                su.p2.off[s + 1] = acc;
            }
            if (acc > CAP) fb = 1;
            su.p2.fb = fb;
            su.p2.lcnt = 0u;
        }
        __syncthreads();
        int C;
        if (!su.p2.fb) {
            // gather the B0-superset (contains exact top-PRE since b* >= B0)
            C = su.p2.off[NSLICE];
            for (int s = 0; s < NSLICE; ++s) {
                const int o = su.p2.off[s], cs = su.p2.off[s + 1] - o;
                const unsigned long long* cp = cand + (size_t)(n * NSLICE + s) * RCAP;
                for (int t = tid; t < cs; t += 1024) su.p2.sk[o + t] = cp[t];
            }
        } else {
            // exact-slow fallback (never expected): rescan with exact b*
            const int bs = su.p2.bs;
            const float* op = obj + (size_t)n * HWA;
            for (int e = tid; e < HWA; e += 1024) {
                float x = op[e];
                if (logit_bin(x) >= bs) {
                    unsigned p = atomicAdd(&su.p2.lcnt, 1u);
                    if (p < CAP) su.p2.sk[p] = mk_key(x, e);
                }
            }
            __syncthreads();
            C = (int)((su.p2.lcnt < CAP) ? su.p2.lcnt : CAP);
        }
        const int NEL = (C <= 2048) ? 2048 : CAP;
        for (int t = tid; t < NEL; t += 1024) if (t >= C) su.p2.sk[t] = 0ull;
        __syncthreads();
        // bitonic sort (desc)
        for (int k = 2; k <= NEL; k <<= 1) {
            for (int j = k >> 1; j > 0; j >>= 1) {
                for (int p = tid; p < (NEL >> 1); p += 1024) {
                    int t = ((p & ~(j - 1)) << 1) | (p & (j - 1));
                    int ixj = t | j;
                    unsigned long long a = su.p2.sk[t], b = su.p2.sk[ixj];
                    bool up = (t & k) == 0;
                    if (up ? (a < b) : (a > b)) { su.p2.sk[t] = b; su.p2.sk[ixj] = a; }
                }
                __syncthreads();
            }
        }
        // decode top PRE (bit-exact vs reference f32 math; verified R1-R8)
        const float* dp = deltas + (size_t)n * (NA * 4 * HW);
        for (int t = tid; t < PRE; t += 1024) {
            unsigned long long key = su.p2.sk[t];
            unsigned sb = (unsigned)(key >> 32);
            unsigned j  = 0xFFFFFFFFu - (unsigned)(key & 0xFFFFFFFFull);
            float s = __uint_as_float(sb);
            int a  = (int)(j % NA), hw = (int)(j / NA);
            int gy = hw / GW, gx = hw % GW;
            int r  = a / 5, si = a % 5;
            float ratio = (r == 0) ? 0.5f : ((r == 1) ? 1.0f : 2.0f);
            float hr = __fsqrt_rn(ratio);
            float wr = __fdiv_rn(1.0f, hr);
            float scale = (float)(32 << si);
            float wsz = __fmul_rn(wr, scale);
            float hsz = __fmul_rn(hr, scale);
            float bx1 = rintf(__fmul_rn(-wsz, 0.5f));
            float by1 = rintf(__fmul_rn(-hsz, 0.5f));
            float bx2 = rintf(__fmul_rn(wsz, 0.5f));
            float by2 = rintf(__fmul_rn(hsz, 0.5f));
            float sx = (float)(gx * 16), sy = (float)(gy * 16);
            float ax1 = sx + bx1, ay1 = sy + by1, ax2 = sx + bx2, ay2 = sy + by2;
            float wa = __fsub_rn(ax2, ax1), ha = __fsub_rn(ay2, ay1);
            float cxa = __fadd_rn(ax1, __fmul_rn(0.5f, wa));
            float cya = __fadd_rn(ay1, __fmul_rn(0.5f, ha));
            int off = gy * GW + gx;
            float dx = dp[(a * 4 + 0) * HW + off];
            float dy = dp[(a * 4 + 1) * HW + off];
            float dw = fminf(dp[(a * 4 + 2) * HW + off], BBOX_CLIP_F);
            float dh = fminf(dp[(a * 4 + 3) * HW + off], BBOX_CLIP_F);
            float cx = __fadd_rn(__fmul_rn(dx, wa), cxa);
            float cy = __fadd_rn(__fmul_rn(dy, ha), cya);
            float bw = __fmul_rn(ref_exp_f32(dw), wa);
            float bh = __fmul_rn(ref_exp_f32(dh), ha);
            float hbw = __fmul_rn(0.5f, bw), hbh = __fmul_rn(0.5f, bh);
            float x1 = fminf(fmaxf(__fsub_rn(cx, hbw), 0.0f), IMGSZ);
            float y1 = fminf(fmaxf(__fsub_rn(cy, hbh), 0.0f), IMGSZ);
            float x2 = fminf(fmaxf(__fadd_rn(cx, hbw), 0.0f), IMGSZ);
            float y2 = fminf(fmaxf(__fadd_rn(cy, hbh), 0.0f), IMGSZ);
            float* tb = topb + ((size_t)n * PRE + t) * 4;
            tb[0] = x1; tb[1] = y1; tb[2] = x2; tb[3] = y2;
            bool valid = (__fsub_rn(x2, x1) >= 1e-3f) && (__fsub_rn(y2, y1) >= 1e-3f);
            tops[(size_t)n * PRE + t] = valid ? s : -1.0f;
        }
    }
    grid.sync();

    // ================= PHASE 3: IoU bitmask (256 tasks, 64 rows each) ========
    for (int task = blockIdx.x; task < 256; task += NBLK) {
        const int n = task & 7, rowblk = task >> 3;
        __syncthreads();   // prior iteration's reads done before restage
        const float4* tb4 = (const float4*)(topb + (size_t)n * PRE * 4);
        for (int t = tid; t < PRE; t += 1024) {
            float4 b = tb4[t];
            su.p3.X1[t] = b.x; su.p3.Y1[t] = b.y; su.p3.X2[t] = b.z; su.p3.Y2[t] = b.w;
        }
        __syncthreads();
        const int wave = tid >> 6, lane = tid & 63;
        for (int rr = 0; rr < 4; ++rr) {
            int i = rowblk * 64 + wave * 4 + rr;
            if (i >= PRE) break;     // wave-uniform
            float bi0 = su.p3.X1[i], bi1 = su.p3.Y1[i];
            float bi2 = su.p3.X2[i], bi3 = su.p3.Y2[i];
            float ai = __fmul_rn(__fsub_rn(bi2, bi0), __fsub_rn(bi3, bi1));
            unsigned long long* mrow = mask + ((size_t)n * MROWS + i) * 32;
            unsigned long long mval = 0ull;
            const int c0 = i >> 6;
            for (int c = c0; c < 32; ++c) {
                int j = c * 64 + lane;
                bool bit = false;
                if (j < PRE && j > i) {
                    float bj0 = su.p3.X1[j], bj1 = su.p3.Y1[j];
                    float bj2 = su.p3.X2[j], bj3 = su.p3.Y2[j];
                    float aj = __fmul_rn(__fsub_rn(bj2, bj0), __fsub_rn(bj3, bj1));
                    float ltx = fmaxf(bi0, bj0), lty = fmaxf(bi1, bj1);
                    float rbx = fminf(bi2, bj2), rby = fminf(bi3, bj3);
                    float ww = fmaxf(__fsub_rn(rbx, ltx), 0.0f);
                    float hh = fmaxf(__fsub_rn(rby, lty), 0.0f);
                    float inter = __fmul_rn(ww, hh);
                    float denom = __fadd_rn(__fsub_rn(__fadd_rn(ai, aj), inter), 1e-6f);
                    bit = __fdiv_rn(inter, denom) > 0.7f;
                }
                unsigned long long m = __ballot(bit);
                if (lane == c) mval = m;
            }
            if (lane < 32) mrow[lane] = mval;
        }
    }
    grid.sync();

    // ================= PHASE 4: greedy NMS + output (verbatim R8) ============
    if (blockIdx.x < NIMG) {
        const int n = blockIdx.x;
        const float* sp = tops + (size_t)n * PRE;
        if (tid < 64) {
            const int lane = tid;
            const unsigned long long* mb = mask + (size_t)n * MROWS * 32;
            #pragma unroll
            for (int k = 0; k < 8; ++k)
                gl_lds16((const char*)sp + k * 1024 + lane * 16,
                         (char*)su.p4.sval + k * 1024);
            WAIT_VM(0);
            unsigned long long vbit = 0ull;
            #pragma unroll
            for (int w = 0; w < 32; ++w) {
                int i = w * 64 + lane;
                bool v = (i < PRE) && (su.p4.sval[i] > -0.5f);
                unsigned long long m = __ballot(v);
                if (lane == w) vbit = m;
            }
            #pragma unroll
            for (int k = 0; k < 16; ++k)
                gl_lds16((const char*)mb + k * 1024 + lane * 16,
                         (char*)&su.p4.sbuf[0][0] + k * 1024);
            #pragma unroll
            for (int k = 0; k < 16; ++k)
                gl_lds16((const char*)(mb + (size_t)64 * 32) + k * 1024 + lane * 16,
                         (char*)&su.p4.sbuf[1][0] + k * 1024);

            unsigned long long remv = 0ull;
            int kc = 0;
            for (int g = 0; g < 32; ++g) {
                const int base = g * 64;
                WAIT_VM(16);
                const unsigned long long* sb = su.p4.sbuf[g & 1];
                unsigned long long rr = sb[(size_t)lane * 32 + g];
                unsigned long long cc = rl64(remv, g);
                unsigned long long vb = rl64(vbit, g);
                unsigned long long todo = vb & ~cc;
                unsigned long long kb = 0ull;
                while (todo) {
                    int jj = (int)__builtin_ctzll(todo);
                    unsigned long long bit = 1ull << jj;
                    kb |= bit;
                    unsigned long long sup = rl64(rr, jj);
                    todo &= ~(sup | bit);
                }
                if (kb) {
                    if ((kb >> lane) & 1ull) {
                        int rank = __popcll(kb & ((1ull << lane) - 1ull));
                        int pos = kc + rank;
                        if (pos < POST) su.p4.kept[pos] = (unsigned short)(base + lane);
                    }
                    kc += __popcll(kb);
                }
                if (kc >= POST || g == 31) break;
                if (kb) {
                    int h = lane >> 5, c = lane & 31;
                    unsigned kbl = (unsigned)(h ? (kb >> 32) : kb);
                    unsigned long long acc = 0ull;
                    #pragma unroll
                    for (int q = 0; q < 32; ++q) {
                        unsigned long long v = sb[(h * 32 + q) * 32 + c];
                        acc |= ((kbl >> q) & 1u) ? v : 0ull;
                    }
                    acc |= __shfl(acc, lane ^ 32);
                    remv |= acc;
                }
                WAIT_LGKM0;
                if (g + 2 < 32) {
                    const char* gb = (const char*)(mb + (size_t)(g + 2) * 64 * 32);
                    char* lb = (char*)&su.p4.sbuf[g & 1][0];
                    #pragma unroll
                    for (int k = 0; k < 16; ++k)
                        gl_lds16(gb + k * 1024 + lane * 16, lb + k * 1024);
                }
            }
            if (lane == 0) su.p4.cnt = (kc < POST) ? kc : POST;
        }
        __syncthreads();
        const int kc = su.p4.cnt;
        for (int rI = tid; rI < POST; rI += 1024) {
            float o0 = 0.f, o1 = 0.f, o2 = 0.f, o3 = 0.f, o4 = 0.f;
            if (rI < kc) {
                int i = su.p4.kept[rI];
                const float* tb = topb + ((size_t)n * PRE + i) * 4;
                o0 = tb[0]; o1 = tb[1]; o2 = tb[2]; o3 = tb[3]; o4 = su.p4.sval[i];
            }
            float* op = out + ((size_t)n * POST + rI) * 5;
            op[0] = o0; op[1] = o1; op[2] = o2; op[3] = o3; op[4] = o4;
        }
    }
}

extern "C" void kernel_launch(void* const* d_in, const int* in_sizes, int n_in,
                              void* d_out, int out_size, void* d_ws, size_t ws_size,
                              hipStream_t stream) {
    const float* obj    = (const float*)d_in[0];   // [8,15,100,100]
    const float* deltas = (const float*)d_in[1];   // [8,60,100,100]
    float* out = (float*)d_out;                    // [8,1000,5]
    char* ws = (char*)d_ws;

    unsigned*            pcnt  = (unsigned*)(ws + WS_PCNT);
    unsigned long long*  cand  = (unsigned long long*)(ws + WS_CAND);
    unsigned*            phist = (unsigned*)(ws + WS_PHIST);
    float*               topb  = (float*)(ws + WS_TOPB);
    float*               tops  = (float*)(ws + WS_TOPS);
    unsigned long long*  mask  = (unsigned long long*)(ws + WS_MASK);

    void* args[] = {(void*)&obj, (void*)&deltas, (void*)&pcnt, (void*)&cand,
                    (void*)&phist, (void*)&topb, (void*)&tops, (void*)&mask,
                    (void*)&out};
    hipLaunchCooperativeKernel((const void*)mega, dim3(NBLK), dim3(1024),
                               args, 0, stream);
}

// Round 10
// 226.997 us; speedup vs baseline: 1.2672x; 1.2672x over previous
//
#include <hip/hip_runtime.h>
#include <math.h>

// ---------------- problem constants ----------------
#define NIMG   8
#define NA     15
#define GH     100
#define GW     100
#define HW     10000
#define HWA    150000      // NA*HW
#define NSLICE 12
#define F4S    3125        // float4s per slice
#define SLEN   12500       // elements per slice
#define PRE    2000
#define POST   1000
#define CAP    4096        // sort buffer capacity
#define RCAP   512         // per-slice candidate region (mean ~284, 13 sigma)
#define NBINS  2048
#define MROWS  2048        // mask rows per image (padded past PRE)
#define B0     1365        // conservative bin cutoff = logit_bin(2.0); exact b* ~1402
#define BBOX_CLIP_F 4.135166556742356f
#define IMGSZ  1600.0f
#define BINSCALE 170.6666667f   // NBINS / 12 over logit range [-6,6]

// ---------------- workspace layout (bytes) ----------------
// No init needed: every consumed byte is written by a producer kernel each call.
#define WS_PCNT   0u            // u32 [96]             384
#define WS_CAND   384u          // u64 [96][512]        393216 -> 393600
#define WS_PHIST  393600u       // u32 [96][2048]       786432 -> 1180032
#define WS_TOPB   1180032u      // f32 [8][2000][4]     256000 -> 1436032
#define WS_TOPS   1436032u      // f32 [8][2000]        64000  -> 1500032 (+256 pad)
#define WS_MASK   1500288u      // u64 [8][2048][32]    4194304 -> 5694592

// s_waitcnt imm: vmcnt[3:0]+[15:14], expcnt[6:4]=7 (ignore), lgkmcnt[11:8]=15 (ignore)
#define WAIT_VM(n) __builtin_amdgcn_s_waitcnt(((n)&15)|(((n)>>4)<<14)|0xF70)
#define WAIT_LGKM0 __builtin_amdgcn_s_waitcnt(0xC07F)   // lgkmcnt(0), vmcnt=63

// async global->LDS DMA, 16 B/lane, zero VGPR results
__device__ __forceinline__ void gl_lds16(const void* g, void* l) {
    __builtin_amdgcn_global_load_lds(
        (const __attribute__((address_space(1))) unsigned int*)g,
        (__attribute__((address_space(3))) unsigned int*)l, 16, 0, 0);
}

// Correctly-rounded f32 exp via double, feeding an IEEE f32 add/div chain.
// Models CPU-reference sigmoid. VERIFIED bit-exact R1-R9.
__device__ __forceinline__ float ref_exp_f32(float x) {
    return (float)exp((double)x);
}
__device__ __forceinline__ float ref_sigmoid(float x) {
    float t = ref_exp_f32(-x);
    return __fdiv_rn(1.0f, __fadd_rn(1.0f, t));
}

// monotone logit->bin map
__device__ __forceinline__ int logit_bin(float x) {
    int b = (int)floorf(__fmul_rn(__fadd_rn(x, 6.0f), BINSCALE));
    return max(0, min(NBINS - 1, b));
}

// 64-bit wave-uniform broadcast via scalar readlane
__device__ __forceinline__ unsigned long long rl64(unsigned long long v, int l) {
    unsigned lo = (unsigned)__builtin_amdgcn_readlane((int)(unsigned)v, l);
    unsigned hi = (unsigned)__builtin_amdgcn_readlane((int)(unsigned)(v >> 32), l);
    return ((unsigned long long)hi << 32) | (unsigned long long)lo;
}

__device__ __forceinline__ unsigned long long mk_key(float x, int e) {
    unsigned sb = __float_as_uint(ref_sigmoid(x));
    unsigned j = (unsigned)((e % HW) * NA + e / HW);   // flat anchor index
    return ((unsigned long long)sb << 32) | (unsigned long long)(0xFFFFFFFFu - j);
}

// ---- K1: fused hist + B0-compact, single obj scan, zero global atomics ----
// grid (NIMG, NSLICE): linear id = n + NIMG*slice -> image n pinned per XCD
__global__ void __launch_bounds__(1024) k_scan(
        const float* __restrict__ obj,
        unsigned* __restrict__ phist,
        unsigned long long* __restrict__ cand,
        unsigned* __restrict__ pcnt) {
    __shared__ unsigned lh[NBINS];                 // 8 KB
    __shared__ unsigned long long lbuf[RCAP];      // 4 KB
    __shared__ unsigned lcnt_sh;
    const int n = blockIdx.x, slice = blockIdx.y, tid = threadIdx.x;
    for (int t = tid; t < NBINS; t += 1024) lh[t] = 0u;
    if (tid == 0) lcnt_sh = 0u;
    __syncthreads();
    const float4* op4 = (const float4*)(obj + (size_t)n * HWA) + (size_t)slice * F4S;
    const int ebase = slice * SLEN;
    for (int t = tid; t < F4S; t += 1024) {
        float4 v = op4[t];
        float xs[4] = {v.x, v.y, v.z, v.w};
        #pragma unroll
        for (int k = 0; k < 4; ++k) {
            int b = logit_bin(xs[k]);
            atomicAdd(&lh[b], 1u);
            if (b >= B0) {
                unsigned p = atomicAdd(&lcnt_sh, 1u);
                if (p < RCAP) lbuf[p] = mk_key(xs[k], ebase + t * 4 + k);
            }
        }
    }
    __syncthreads();
    const int r = n * NSLICE + slice;
    unsigned* ph = phist + (size_t)r * NBINS;
    for (int t = tid; t < NBINS; t += 1024) ph[t] = lh[t];
    const unsigned L = lcnt_sh;
    if (tid == 0) pcnt[r] = L;                 // raw (may exceed RCAP -> fallback)
    const unsigned Lc = (L < RCAP) ? L : RCAP;
    unsigned long long* cp = cand + (size_t)r * RCAP;
    for (unsigned t = tid; t < Lc; t += 1024) cp[t] = lbuf[t];
}

// ---- K2: exact b* + score-threshold filter gather + bitonic 2048 + decode ----
__global__ void __launch_bounds__(1024) k_sort_decode(
        const float* __restrict__ obj,
        const unsigned* __restrict__ pcnt,
        const unsigned long long* __restrict__ cand,
        const unsigned* __restrict__ phist,
        const float* __restrict__ deltas,
        float* __restrict__ topb,
        float* __restrict__ tops) {
    __shared__ unsigned shist[NBINS];              // 8 KB
    __shared__ unsigned long long sk[CAP];         // 32 KB
    __shared__ unsigned lcnt_sh, st_sh;
    __shared__ int bs_sh, fb_sh, off_sh[NSLICE + 1];
    const int n = blockIdx.x, tid = threadIdx.x;
    // sum the 12 partial hists
    const unsigned* ph = phist + (size_t)n * NSLICE * NBINS;
    for (int b = tid; b < NBINS; b += 1024) {
        unsigned s = 0;
        #pragma unroll
        for (int k = 0; k < NSLICE; ++k) s += ph[k * NBINS + b];
        shist[b] = s;
    }
    if (tid == 0) lcnt_sh = 0u;
    __syncthreads();
    // wave 0: b* = max{b : sum_{x>=b} hist[x] >= PRE} (0 if total < PRE)
    if (tid < 64) {
        const int lane = tid;
        unsigned v[32]; unsigned S = 0;
        #pragma unroll
        for (int t = 0; t < 32; ++t) { v[t] = shist[lane * 32 + t]; S += v[t]; }
        unsigned T = S;
        #pragma unroll
        for (int d = 1; d < 64; d <<= 1) {
            unsigned u = __shfl_down(T, d);
            if (lane + d < 64) T += u;
        }
        unsigned Tn = T - S;
        int bestt = -1; unsigned W = 0;
        #pragma unroll
        for (int t = 31; t >= 0; --t) {
            W += v[t];
            if (bestt < 0 && W + Tn >= PRE) bestt = t;
        }
        unsigned long long hm = __ballot(bestt >= 0);
        int bs = 0;
        if (hm != 0ull) {
            int hl = 63 - __builtin_clzll(hm);
            int bt = __builtin_amdgcn_readlane(bestt, hl);
            bs = hl * 32 + bt;
        }
        if (lane == 0) {
            bs_sh = bs;
            // score-bits threshold: x >= xt implies bin >= b* candidates included;
            // 2e-3 down-nudge (~1/3 bin) guarantees a superset (~+10 elements)
            float xt = __fsub_rn(__fsub_rn(__fdiv_rn((float)bs, BINSCALE), 6.0f),
                                 2.0e-3f);
            st_sh = __float_as_uint(ref_sigmoid(xt));
        }
    }
    if (tid < NSLICE) off_sh[tid + 1] = (int)pcnt[n * NSLICE + tid];
    __syncthreads();
    if (tid == 0) {
        int fb = (bs_sh < B0) ? 1 : 0;         // B0 was not conservative enough
        int acc = 0; off_sh[0] = 0;
        for (int s = 0; s < NSLICE; ++s) {
            int c = off_sh[s + 1];
            if (c > RCAP) fb = 1;              // slice region overflow
            acc += (c > RCAP) ? RCAP : c;
            off_sh[s + 1] = acc;
        }
        if (acc > CAP) fb = 1;
        fb_sh = fb;
    }
    __syncthreads();
    int C;
    if (!fb_sh) {
        // filtered gather: keep keys with score_bits >= threshold (superset of
        // the exact bin>=b* set; ~2040 elements -> 2048-sort)
        const unsigned st = st_sh;
        for (int s = 0; s < NSLICE; ++s) {
            const int o = off_sh[s], cs = off_sh[s + 1] - o;
            const unsigned long long* cp = cand + (size_t)(n * NSLICE + s) * RCAP;
            for (int t = tid; t < cs; t += 1024) {
                unsigned long long key = cp[t];
                if ((unsigned)(key >> 32) >= st) {
                    unsigned p = atomicAdd(&lcnt_sh, 1u);
                    sk[p] = key;               // p < total <= CAP guaranteed
                }
            }
        }
        __syncthreads();
        C = (int)lcnt_sh;
        if (C > 2048) {                        // filter insufficient: unfiltered 4096
            __syncthreads();
            for (int s = 0; s < NSLICE; ++s) {
                const int o = off_sh[s], cs = off_sh[s + 1] - o;
                const unsigned long long* cp = cand + (size_t)(n * NSLICE + s) * RCAP;
                for (int t = tid; t < cs; t += 1024) sk[o + t] = cp[t];
            }
            C = off_sh[NSLICE];
        }
    } else {
        // exact-slow fallback (never expected): rescan with exact b*
        const int bs = bs_sh;
        const float* op = obj + (size_t)n * HWA;
        for (int e = tid; e < HWA; e += 1024) {
            float x = op[e];
            if (logit_bin(x) >= bs) {
                unsigned p = atomicAdd(&lcnt_sh, 1u);
                if (p < CAP) sk[p] = mk_key(x, e);
            }
        }
        __syncthreads();
        C = (int)((lcnt_sh < CAP) ? lcnt_sh : CAP);
    }
    const int NEL = (C <= 2048) ? 2048 : CAP;
    __syncthreads();
    for (int t = tid; t < NEL; t += 1024) if (t >= C) sk[t] = 0ull;
    __syncthreads();
    // bitonic sort (desc)
    for (int k = 2; k <= NEL; k <<= 1) {
        for (int j = k >> 1; j > 0; j >>= 1) {
            for (int p = tid; p < (NEL >> 1); p += 1024) {
                int t = ((p & ~(j - 1)) << 1) | (p & (j - 1));
                int ixj = t | j;
                unsigned long long a = sk[t], b = sk[ixj];
                bool up = (t & k) == 0;
                if (up ? (a < b) : (a > b)) { sk[t] = b; sk[ixj] = a; }
            }
            __syncthreads();
        }
    }
    // decode top PRE (bit-exact vs reference f32 math; verified R1-R9)
    const float* dp = deltas + (size_t)n * (NA * 4 * HW);
    for (int t = tid; t < PRE; t += 1024) {
        unsigned long long key = sk[t];
        unsigned sb = (unsigned)(key >> 32);
        unsigned j  = 0xFFFFFFFFu - (unsigned)(key & 0xFFFFFFFFull);
        float s = __uint_as_float(sb);
        int a  = (int)(j % NA), hw = (int)(j / NA);
        int gy = hw / GW, gx = hw % GW;
        int r  = a / 5, si = a % 5;
        float ratio = (r == 0) ? 0.5f : ((r == 1) ? 1.0f : 2.0f);
        float hr = __fsqrt_rn(ratio);
        float wr = __fdiv_rn(1.0f, hr);
        float scale = (float)(32 << si);
        float wsz = __fmul_rn(wr, scale);
        float hsz = __fmul_rn(hr, scale);
        float bx1 = rintf(__fmul_rn(-wsz, 0.5f));
        float by1 = rintf(__fmul_rn(-hsz, 0.5f));
        float bx2 = rintf(__fmul_rn(wsz, 0.5f));
        float by2 = rintf(__fmul_rn(hsz, 0.5f));
        float sx = (float)(gx * 16), sy = (float)(gy * 16);
        float ax1 = sx + bx1, ay1 = sy + by1, ax2 = sx + bx2, ay2 = sy + by2;
        float wa = __fsub_rn(ax2, ax1), ha = __fsub_rn(ay2, ay1);
        float cxa = __fadd_rn(ax1, __fmul_rn(0.5f, wa));
        float cya = __fadd_rn(ay1, __fmul_rn(0.5f, ha));
        int off = gy * GW + gx;
        float dx = dp[(a * 4 + 0) * HW + off];
        float dy = dp[(a * 4 + 1) * HW + off];
        float dw = fminf(dp[(a * 4 + 2) * HW + off], BBOX_CLIP_F);
        float dh = fminf(dp[(a * 4 + 3) * HW + off], BBOX_CLIP_F);
        float cx = __fadd_rn(__fmul_rn(dx, wa), cxa);
        float cy = __fadd_rn(__fmul_rn(dy, ha), cya);
        float bw = __fmul_rn(ref_exp_f32(dw), wa);
        float bh = __fmul_rn(ref_exp_f32(dh), ha);
        float hbw = __fmul_rn(0.5f, bw), hbh = __fmul_rn(0.5f, bh);
        float x1 = fminf(fmaxf(__fsub_rn(cx, hbw), 0.0f), IMGSZ);
        float y1 = fminf(fmaxf(__fsub_rn(cy, hbh), 0.0f), IMGSZ);
        float x2 = fminf(fmaxf(__fadd_rn(cx, hbw), 0.0f), IMGSZ);
        float y2 = fminf(fmaxf(__fadd_rn(cy, hbh), 0.0f), IMGSZ);
        float* tb = topb + ((size_t)n * PRE + t) * 4;
        tb[0] = x1; tb[1] = y1; tb[2] = x2; tb[3] = y2;
        bool valid = (__fsub_rn(x2, x1) >= 1e-3f) && (__fsub_rn(y2, y1) >= 1e-3f);
        tops[(size_t)n * PRE + t] = valid ? s : -1.0f;
    }
}

// ---- K3: 2000x2000 IoU suppression bitmask (bit j of row i: j>i && iou>0.7) ----
// chunks c < i>>6 are all-zero by j>i -> start there, ~1.9x less work. (R8 proven)
__global__ void k_iou(const float* __restrict__ topb,
                      unsigned long long* __restrict__ mask) {
    __shared__ float X1[PRE], Y1[PRE], X2[PRE], Y2[PRE];
    const int n = blockIdx.x, rowblk = blockIdx.y, tid = threadIdx.x;
    const float4* tb4 = (const float4*)(topb + (size_t)n * PRE * 4);
    for (int t = tid; t < PRE; t += 256) {
        float4 b = tb4[t];
        X1[t] = b.x; Y1[t] = b.y; X2[t] = b.z; Y2[t] = b.w;
    }
    __syncthreads();
    const int wave = tid >> 6, lane = tid & 63;
    for (int rr = 0; rr < 8; ++rr) {
        int i = rowblk * 32 + wave * 8 + rr;
        if (i >= PRE) break;
        float bi0 = X1[i], bi1 = Y1[i], bi2 = X2[i], bi3 = Y2[i];
        float ai = __fmul_rn(__fsub_rn(bi2, bi0), __fsub_rn(bi3, bi1));
        unsigned long long* mrow = mask + ((size_t)n * MROWS + i) * 32;
        unsigned long long mval = 0ull;     // lane c<32 collects chunk c
        const int c0 = i >> 6;
        for (int c = c0; c < 32; ++c) {
            int j = c * 64 + lane;
            bool bit = false;
            if (j < PRE && j > i) {
                float bj0 = X1[j], bj1 = Y1[j], bj2 = X2[j], bj3 = Y2[j];
                float aj = __fmul_rn(__fsub_rn(bj2, bj0), __fsub_rn(bj3, bj1));
                float ltx = fmaxf(bi0, bj0), lty = fmaxf(bi1, bj1);
                float rbx = fminf(bi2, bj2), rby = fminf(bi3, bj3);
                float ww = fmaxf(__fsub_rn(rbx, ltx), 0.0f);
                float hh = fmaxf(__fsub_rn(rby, lty), 0.0f);
                float inter = __fmul_rn(ww, hh);
                float denom = __fadd_rn(__fsub_rn(__fadd_rn(ai, aj), inter), 1e-6f);
                bit = __fdiv_rn(inter, denom) > 0.7f;
            }
            unsigned long long m = __ballot(bit);
            if (lane == c) mval = m;
        }
        if (lane < 32) mrow[lane] = mval;   // one coalesced 256B store per row
    }
}

// ---- K4: greedy NMS. nz-skip serial chain (readlanes only for the ~3% of rows
// with in-group suppression); LDS-staged mask via DMA; parallel kept-emission.
__global__ void __launch_bounds__(256) k_nms_out(
        const float* __restrict__ topb,
        const float* __restrict__ tops,
        const unsigned long long* __restrict__ mask,
        float* __restrict__ out) {
    __shared__ unsigned long long sbuf[2][2048];   // 2 x 16 KB staging (64 rows each)
    __shared__ float sval[2048];                   // scores (8 KB)
    __shared__ unsigned short kept[POST];
    __shared__ int cnt;
    const int n = blockIdx.x, tid = threadIdx.x;   // 256 threads; wave 0 does NMS
    const float* sp = tops + (size_t)n * PRE;
    if (tid < 64) {
        const int lane = tid;
        const unsigned long long* mb = mask + (size_t)n * MROWS * 32;
        // stage scores via DMA (reads 192 B past tops[n] slice: inside ws pad)
        #pragma unroll
        for (int k = 0; k < 8; ++k)
            gl_lds16((const char*)sp + k * 1024 + lane * 16, (char*)sval + k * 1024);
        WAIT_VM(0);
        unsigned long long vbit = 0ull;   // lane w<32: validity of rows [64w,64w+64)
        #pragma unroll
        for (int w = 0; w < 32; ++w) {
            int i = w * 64 + lane;
            bool v = (i < PRE) && (sval[i] > -0.5f);
            unsigned long long m = __ballot(v);
            if (lane == w) vbit = m;
        }
        // prologue: stage groups 0 and 1
        #pragma unroll
        for (int k = 0; k < 16; ++k)
            gl_lds16((const char*)mb + k * 1024 + lane * 16,
                     (char*)&sbuf[0][0] + k * 1024);
        #pragma unroll
        for (int k = 0; k < 16; ++k)
            gl_lds16((const char*)(mb + (size_t)64 * 32) + k * 1024 + lane * 16,
                     (char*)&sbuf[1][0] + k * 1024);

        unsigned long long remv = 0ull;   // lane l owns suppression chunk (l&31)
        int kc = 0;
        for (int g = 0; g < 32; ++g) {
            const int base = g * 64;
            WAIT_VM(16);                   // stage(g) done; stage(g+1) may fly
            const unsigned long long* sb = sbuf[g & 1];
            // row (base+lane)'s chunk g (in-group suppression slice; bits > lane)
            unsigned long long rr = sb[(size_t)lane * 32 + g];
            unsigned long long nz = __ballot(rr != 0ull);  // rows w/ in-group bits
            unsigned long long cc = rl64(remv, g);
            unsigned long long vb = rl64(vbit, g);
            unsigned long long todo = vb & ~cc;
            unsigned long long kb = 0ull;
            while (todo) {
                int jj = (int)__builtin_ctzll(todo);
                unsigned long long bit = 1ull << jj;
                kb |= bit;
                todo &= ~bit;
                if (nz & bit) {            // rare (~3%): row jj suppresses in-group
                    unsigned long long sup = rl64(rr, jj);
                    todo &= ~sup;
                }
            }
            // parallel emission: rank by popcount-below
            if (kb) {
                if ((kb >> lane) & 1ull) {
                    int rank = __popcll(kb & ((1ull << lane) - 1ull));
                    int pos = kc + rank;
                    if (pos < POST) kept[pos] = (unsigned short)(base + lane);
                }
                kc += __popcll(kb);
            }
            if (kc >= POST || g == 31) break;   // future groups irrelevant
            // fold kept rows' full masks into remv (off the decision chain)
            if (kb) {
                int h = lane >> 5, c = lane & 31;
                unsigned kbl = (unsigned)(h ? (kb >> 32) : kb);
                unsigned long long acc = 0ull;
                #pragma unroll
                for (int q = 0; q < 32; ++q) {
                    unsigned long long v = sb[(h * 32 + q) * 32 + c];
                    acc |= ((kbl >> q) & 1u) ? v : 0ull;
                }
                acc |= __shfl(acc, lane ^ 32);   // merge row-halves
                remv |= acc;
            }
            WAIT_LGKM0;                      // LDS reads done before DMA overwrites
            if (g + 2 < 32) {                // stage(g+2) into same-parity buffer
                const char* gb = (const char*)(mb + (size_t)(g + 2) * 64 * 32);
                char* lb = (char*)&sbuf[g & 1][0];
                #pragma unroll
                for (int k = 0; k < 16; ++k)
                    gl_lds16(gb + k * 1024 + lane * 16, lb + k * 1024);
            }
        }
        if (lane == 0) cnt = (kc < POST) ? kc : POST;
    }
    __syncthreads();
    const int kc = cnt;
    for (int rI = tid; rI < POST; rI += 256) {
        float o0 = 0.f, o1 = 0.f, o2 = 0.f, o3 = 0.f, o4 = 0.f;
        if (rI < kc) {
            int i = kept[rI];
            const float* tb = topb + ((size_t)n * PRE + i) * 4;
            o0 = tb[0]; o1 = tb[1]; o2 = tb[2]; o3 = tb[3]; o4 = sval[i];
        }
        float* op = out + ((size_t)n * POST + rI) * 5;
        op[0] = o0; op[1] = o1; op[2] = o2; op[3] = o3; op[4] = o4;
    }
}

extern "C" void kernel_launch(void* const* d_in, const int* in_sizes, int n_in,
                              void* d_out, int out_size, void* d_ws, size_t ws_size,
                              hipStream_t stream) {
    const float* obj    = (const float*)d_in[0];   // [8,15,100,100]
    const float* deltas = (const float*)d_in[1];   // [8,60,100,100]
    float* out = (float*)d_out;                    // [8,1000,5]
    char* ws = (char*)d_ws;

    unsigned*            pcnt  = (unsigned*)(ws + WS_PCNT);
    unsigned long long*  cand  = (unsigned long long*)(ws + WS_CAND);
    unsigned*            phist = (unsigned*)(ws + WS_PHIST);
    float*               topb  = (float*)(ws + WS_TOPB);
    float*               tops  = (float*)(ws + WS_TOPS);
    unsigned long long*  mask  = (unsigned long long*)(ws + WS_MASK);

    k_scan       <<<dim3(NIMG, NSLICE), 1024, 0, stream>>>(obj, phist, cand, pcnt);
    k_sort_decode<<<NIMG, 1024, 0, stream>>>(obj, pcnt, cand, phist, deltas,
                                             topb, tops);
    k_iou        <<<dim3(NIMG, 63), 256, 0, stream>>>(topb, mask);
    k_nms_out    <<<NIMG, 256, 0, stream>>>(topb, tops, mask, out);
}